// Round 4
// baseline (374.983 us; speedup 1.0000x reference)
//
#include <hip/hip_runtime.h>

// Shapes (fixed): B=16 T=8 H=W=14 HW=196 L=197 C=768 Ca=384
#define Cc   768
#define CAc  384
#define Tc   8
#define Hc   14
#define Wc   14
#define HWc  196
#define Lc   197
#define BTc  128
#define Mc   25088

typedef unsigned short u16;
typedef __attribute__((ext_vector_type(4))) float f32x4;
typedef __attribute__((ext_vector_type(4))) short s16x4;
typedef __attribute__((ext_vector_type(8))) short s16x8;

__device__ __forceinline__ u16 f2b(float f) {
  union { float f; unsigned u; } v; v.f = f;
  unsigned r = (v.u + 0x7FFFu + ((v.u >> 16) & 1u)) >> 16;
  return (u16)r;
}
__device__ __forceinline__ float b2f(u16 h) {
  union { unsigned u; float f; } v; v.u = ((unsigned)h) << 16;
  return v.f;
}

// ---- tiled transpose+convert: [K,N] f32 -> [N,K] bf16 ----
__global__ void wt_kernel(const float* __restrict__ wA, u16* __restrict__ wAT,
                          const float* __restrict__ wB, u16* __restrict__ wBT,
                          int K, int N) {
  __shared__ float t[32][33];
  const float* w = blockIdx.z ? wB : wA;
  u16* wT = blockIdx.z ? wBT : wAT;
  int k0 = blockIdx.x * 32, n0 = blockIdx.y * 32;
  int tx = threadIdx.x & 31, ty = threadIdx.x >> 5;   // 32 x 8
  #pragma unroll
  for (int p = 0; p < 4; ++p) {
    int r = ty + p * 8;
    t[r][tx] = w[(long)(k0 + r) * N + n0 + tx];
  }
  __syncthreads();
  #pragma unroll
  for (int p = 0; p < 4; ++p) {
    int r = ty + p * 8;
    wT[(long)(n0 + r) * K + k0 + tx] = f2b(t[tx][r]);
  }
}

// ---- prep: conv taps [Ca, taps] -> [taps, Ca] f32 ----
__global__ void cwt_kernel(const float* __restrict__ cw, float* __restrict__ cwT, int taps) {
  int idx = blockIdx.x * 256 + threadIdx.x;
  if (idx >= taps * CAc) return;
  int t = idx / CAc, c = idx - t * CAc;
  cwT[idx] = cw[c * taps + t];
}

// ---- prep v2: per-thread t-loop; x read once; xb=bf16(xs), db=bf16(xs-prev) ----
__global__ void prep_kernel(const float* __restrict__ x, u16* __restrict__ xb, u16* __restrict__ db) {
  int idx = blockIdx.x * 256 + threadIdx.x;  // 16*196*96 = 301056 threads
  int c8 = idx % 96;
  int rest = idx / 96;
  int hw = rest % HWc;
  int b = rest / HWc;
  int c0 = c8 * 8;
  f32x4 pa, pb;
  #pragma unroll
  for (int t = 0; t < Tc; ++t) {
    long xoff = ((long)(b * Tc + t) * Lc + 1 + hw) * Cc + c0;
    f32x4 ca = *(const f32x4*)(x + xoff);
    f32x4 cb = *(const f32x4*)(x + xoff + 4);
    if (t == 0) { pa = ca; pb = cb; }
    s16x8 xo, dd;
    #pragma unroll
    for (int q = 0; q < 4; ++q) {
      xo[q]     = (short)f2b(ca[q]);
      xo[q + 4] = (short)f2b(cb[q]);
      dd[q]     = (short)f2b(ca[q] - pa[q]);
      dd[q + 4] = (short)f2b(cb[q] - pb[q]);
    }
    long r = (long)(b * Tc + t) * HWc + hw;
    *(s16x8*)(xb + r * Cc + c0) = xo;
    *(s16x8*)(db + r * Cc + c0) = dd;
    pa = ca; pb = cb;
  }
}

// ---- CLS token passthrough ----
__global__ void cls_kernel(const float* __restrict__ x, float* __restrict__ out) {
  int idx = blockIdx.x * 256 + threadIdx.x;
  if (idx >= BTc * (Cc / 4)) return;
  int bt = idx / (Cc / 4);
  int c4 = (idx - bt * (Cc / 4)) * 4;
  long o = (long)bt * Lc * Cc + c4;
  *(f32x4*)(out + o) = *(const f32x4*)(x + o);
}

#define SP 72   // padded LDS row stride (shorts)

// ---- GEMM1: [M,768]bf16 @ [768->384] + bias -> bf16 ; z picks branch ----
__global__ __launch_bounds__(256, 4) void gemm1_kernel(
    const u16* __restrict__ xb, const u16* __restrict__ db,
    const u16* __restrict__ w1T, const u16* __restrict__ ow1T,
    const float* __restrict__ b1v, const float* __restrict__ ob1v,
    u16* __restrict__ y1, u16* __restrict__ o1)
{
  __shared__ u16 lA[128 * SP];
  __shared__ u16 lB[128 * SP];
  const u16* A    = blockIdx.z ? db   : xb;
  const u16* Wt   = blockIdx.z ? ow1T : w1T;
  const float* bv = blockIdx.z ? ob1v : b1v;
  u16* outp       = blockIdx.z ? o1   : y1;

  int tid = threadIdx.x;
  int m0 = blockIdx.x * 128;
  int n0 = blockIdx.y * 128;
  int wave = tid >> 6, lane = tid & 63;
  int wm = (wave >> 1) * 64, wn = (wave & 1) * 64;
  int lrow = lane & 15, lgrp = lane >> 4;
  int srow = tid >> 3;
  int scol = (tid & 7) * 8;

  f32x4 acc[4][4];
  #pragma unroll
  for (int i = 0; i < 4; ++i)
    #pragma unroll
    for (int j = 0; j < 4; ++j) acc[i][j] = (f32x4){0,0,0,0};

  for (int kt = 0; kt < 12; ++kt) {
    int k0 = kt * 64;
    #pragma unroll
    for (int p = 0; p < 4; ++p) {
      int r = p * 32 + srow;
      s16x8 va = *(const s16x8*)(A  + (long)(m0 + r) * Cc + k0 + scol);
      s16x8 vb = *(const s16x8*)(Wt + (long)(n0 + r) * Cc + k0 + scol);
      *(s16x8*)(lA + r * SP + scol) = va;
      *(s16x8*)(lB + r * SP + scol) = vb;
    }
    __syncthreads();
    #pragma unroll
    for (int kk = 0; kk < 2; ++kk) {
      s16x8 af[4], bf[4];
      #pragma unroll
      for (int i = 0; i < 4; ++i) af[i] = *(const s16x8*)(lA + (wm + i * 16 + lrow) * SP + kk * 32 + lgrp * 8);
      #pragma unroll
      for (int j = 0; j < 4; ++j) bf[j] = *(const s16x8*)(lB + (wn + j * 16 + lrow) * SP + kk * 32 + lgrp * 8);
      #pragma unroll
      for (int i = 0; i < 4; ++i)
        #pragma unroll
        for (int j = 0; j < 4; ++j)
          acc[i][j] = __builtin_amdgcn_mfma_f32_16x16x32_bf16(af[i], bf[j], acc[i][j], 0, 0, 0);
    }
    __syncthreads();
  }
  #pragma unroll
  for (int i = 0; i < 4; ++i) {
    #pragma unroll
    for (int j = 0; j < 4; ++j) {
      int n = n0 + wn + j * 16 + lrow;
      float bb = bv[n];
      #pragma unroll
      for (int q = 0; q < 4; ++q) {
        int m = m0 + wm + i * 16 + lgrp * 4 + q;
        outp[(long)m * CAc + n] = f2b(acc[i][j][q] + bb);
      }
    }
  }
}

// ---- GEMM2: out[:,1:,:] = x + c1@w2 + c2@ow2 + b2 + ob2 (f32) ----
__global__ __launch_bounds__(256, 4) void gemm2_kernel(
    const u16* __restrict__ c1, const u16* __restrict__ c2,
    const u16* __restrict__ w2T, const u16* __restrict__ ow2T,
    const float* __restrict__ b2v, const float* __restrict__ ob2v,
    const float* __restrict__ x, float* __restrict__ out)
{
  __shared__ u16 lA[128 * SP];
  __shared__ u16 lB[128 * SP];
  int tid = threadIdx.x;
  int m0 = blockIdx.x * 128;
  int n0 = blockIdx.y * 128;
  int wave = tid >> 6, lane = tid & 63;
  int wm = (wave >> 1) * 64, wn = (wave & 1) * 64;
  int lrow = lane & 15, lgrp = lane >> 4;
  int srow = tid >> 3;
  int scol = (tid & 7) * 8;

  f32x4 acc[4][4];
  #pragma unroll
  for (int i = 0; i < 4; ++i)
    #pragma unroll
    for (int j = 0; j < 4; ++j) acc[i][j] = (f32x4){0,0,0,0};

  for (int kt = 0; kt < 12; ++kt) {
    int half = kt >= 6;
    const u16* Ap = half ? c2 : c1;
    const u16* Wp = half ? ow2T : w2T;
    int k0 = (half ? (kt - 6) : kt) * 64;
    #pragma unroll
    for (int p = 0; p < 4; ++p) {
      int r = p * 32 + srow;
      s16x8 va = *(const s16x8*)(Ap + (long)(m0 + r) * CAc + k0 + scol);
      s16x8 vb = *(const s16x8*)(Wp + (long)(n0 + r) * CAc + k0 + scol);
      *(s16x8*)(lA + r * SP + scol) = va;
      *(s16x8*)(lB + r * SP + scol) = vb;
    }
    __syncthreads();
    #pragma unroll
    for (int kk = 0; kk < 2; ++kk) {
      s16x8 af[4], bf[4];
      #pragma unroll
      for (int i = 0; i < 4; ++i) af[i] = *(const s16x8*)(lA + (wm + i * 16 + lrow) * SP + kk * 32 + lgrp * 8);
      #pragma unroll
      for (int j = 0; j < 4; ++j) bf[j] = *(const s16x8*)(lB + (wn + j * 16 + lrow) * SP + kk * 32 + lgrp * 8);
      #pragma unroll
      for (int i = 0; i < 4; ++i)
        #pragma unroll
        for (int j = 0; j < 4; ++j)
          acc[i][j] = __builtin_amdgcn_mfma_f32_16x16x32_bf16(af[i], bf[j], acc[i][j], 0, 0, 0);
    }
    __syncthreads();
  }
  #pragma unroll
  for (int i = 0; i < 4; ++i) {
    #pragma unroll
    for (int q = 0; q < 4; ++q) {
      int m = m0 + wm + i * 16 + lgrp * 4 + q;
      int bt = m / HWc;
      int hw = m - bt * HWc;
      long base = ((long)bt * Lc + 1 + hw) * Cc;
      #pragma unroll
      for (int j = 0; j < 4; ++j) {
        int n = n0 + wn + j * 16 + lrow;
        out[base + n] = x[base + n] + acc[i][j][q] + b2v[n] + ob2v[n];
      }
    }
  }
}

// ---- depthwise conv, channel-last; XCD-swizzled flat grid over both branches ----
__global__ void conv_kernel(const u16* __restrict__ in1, const float* __restrict__ wT1,
                            const float* __restrict__ bias1, u16* __restrict__ out1,
                            const u16* __restrict__ in2, const float* __restrict__ wT2,
                            const float* __restrict__ bias2, u16* __restrict__ out2)
{
  // grid.x = 3584 = 2 branches x 1792 (bt*h). Bijective XCD swizzle: each of the
  // 8 XCDs gets a contiguous 448-block chunk -> h/t-neighbor blocks share L2.
  int bid = blockIdx.x;
  int swz = (bid & 7) * 448 + (bid >> 3);
  int is3d = swz < 1792;
  int bth = is3d ? swz : swz - 1792;

  const u16* in = is3d ? in1 : in2;
  const float* wT = is3d ? wT1 : wT2;
  const float* bias = is3d ? bias1 : bias2;
  u16* outp = is3d ? out1 : out2;

  int h = bth % Hc;
  int bt = bth / Hc;
  int t = bt % Tc;
  int tid = threadIdx.x;
  int dtlo = is3d ? -1 : 0, dthi = is3d ? 1 : 0;
  for (int it = tid; it < Wc * 48; it += 256) {
    int wq = it / 48;
    int c = (it - wq * 48) * 8;
    float a[8] = {0,0,0,0,0,0,0,0};
    int tap = 0;
    for (int dt = dtlo; dt <= dthi; ++dt) {
      int tt = t + dt;
      bool tok = (tt >= 0) && (tt < Tc);
      for (int dh = -1; dh <= 1; ++dh) {
        int hh = h + dh;
        bool hok = (hh >= 0) && (hh < Hc);
        for (int dw = -1; dw <= 1; ++dw, ++tap) {
          int ww = wq + dw;
          if (!tok || !hok || ww < 0 || ww >= Wc) continue;
          const u16* ip = in + ((long)(bt + dt) * HWc + hh * Wc + ww) * CAc + c;
          s16x8 v = *(const s16x8*)ip;
          const float* wp = wT + tap * CAc + c;
          f32x4 w0 = *(const f32x4*)wp;
          f32x4 w1 = *(const f32x4*)(wp + 4);
          #pragma unroll
          for (int q = 0; q < 4; ++q) {
            a[q]     += b2f((u16)v[q])     * w0[q];
            a[q + 4] += b2f((u16)v[q + 4]) * w1[q];
          }
        }
      }
    }
    s16x8 o;
    #pragma unroll
    for (int q = 0; q < 8; ++q) o[q] = (short)f2b(a[q] + bias[c + q]);
    *(s16x8*)(outp + ((long)bt * HWc + h * Wc + wq) * CAc + c) = o;
  }
}

extern "C" void kernel_launch(void* const* d_in, const int* in_sizes, int n_in,
                              void* d_out, int out_size, void* d_ws, size_t ws_size,
                              hipStream_t stream) {
  const float* x   = (const float*)d_in[0];
  const float* w1  = (const float*)d_in[1];
  const float* b1  = (const float*)d_in[2];
  const float* cw  = (const float*)d_in[3];
  const float* cb  = (const float*)d_in[4];
  const float* w2  = (const float*)d_in[5];
  const float* b2  = (const float*)d_in[6];
  const float* ow1 = (const float*)d_in[7];
  const float* ob1 = (const float*)d_in[8];
  const float* ocw = (const float*)d_in[9];
  const float* ocb = (const float*)d_in[10];
  const float* ow2 = (const float*)d_in[11];
  const float* ob2 = (const float*)d_in[12];
  float* out = (float*)d_out;
  char* ws = (char*)d_ws;

  // workspace layout (bytes)
  u16*  w1T  = (u16*) (ws + 0);          // 589824
  u16*  ow1T = (u16*) (ws + 589824);
  u16*  w2T  = (u16*) (ws + 1179648);
  u16*  ow2T = (u16*) (ws + 1769472);
  float* cwT = (float*)(ws + 2359296);   // 41472
  float* ocwT= (float*)(ws + 2400768);   // 13824
  u16*  xb   = (u16*) (ws + 2414592);    // 38535168
  u16*  db   = (u16*) (ws + 40949760);   // 38535168
  u16*  y1   = (u16*) (ws + 79484928);   // 19267584
  u16*  o1   = (u16*) (ws + 98752512);   // 19267584; end 118020096
  u16*  c1   = (u16*) (ws + 2414592);    // alias xb (dead after gemm1)
  u16*  c2   = (u16*) (ws + 21682176);   // alias xb upper half

  wt_kernel<<<dim3(24, 12, 2), 256, 0, stream>>>(w1, w1T, ow1, ow1T, 768, 384);
  wt_kernel<<<dim3(12, 24, 2), 256, 0, stream>>>(w2, w2T, ow2, ow2T, 384, 768);
  cwt_kernel<<<41, 256, 0, stream>>>(cw, cwT, 27);
  cwt_kernel<<<14, 256, 0, stream>>>(ocw, ocwT, 9);
  cls_kernel<<<96, 256, 0, stream>>>(x, out);
  prep_kernel<<<1176, 256, 0, stream>>>(x, xb, db);
  gemm1_kernel<<<dim3(196, 3, 2), 256, 0, stream>>>(xb, db, w1T, ow1T, b1, ob1, y1, o1);
  conv_kernel<<<3584, 256, 0, stream>>>(y1, cwT, cb, c1, o1, ocwT, ocb, c2);
  gemm2_kernel<<<dim3(196, 6), 256, 0, stream>>>(c1, c2, w2T, ow2T, b2, ob2, x, out);
}

// Round 7
// 315.713 us; speedup vs baseline: 1.1877x; 1.1877x over previous
//
#include <hip/hip_runtime.h>

// Shapes (fixed): B=16 T=8 H=W=14 HW=196 L=197 C=768 Ca=384
#define Cc   768
#define CAc  384
#define Tc   8
#define Hc   14
#define Wc   14
#define HWc  196
#define Lc   197
#define BTc  128
#define Mc   25088

typedef unsigned short u16;
typedef __attribute__((ext_vector_type(4))) float f32x4;
typedef __attribute__((ext_vector_type(4))) short s16x4;
typedef __attribute__((ext_vector_type(8))) short s16x8;

__device__ __forceinline__ u16 f2b(float f) {
  union { float f; unsigned u; } v; v.f = f;
  unsigned r = (v.u + 0x7FFFu + ((v.u >> 16) & 1u)) >> 16;
  return (u16)r;
}
__device__ __forceinline__ float b2f(u16 h) {
  union { unsigned u; float f; } v; v.u = ((unsigned)h) << 16;
  return v.f;
}

// ---- tiled transpose+convert: [K,N] f32 -> [N,K] bf16 ----
__global__ void wt_kernel(const float* __restrict__ wA, u16* __restrict__ wAT,
                          const float* __restrict__ wB, u16* __restrict__ wBT,
                          int K, int N) {
  __shared__ float t[32][33];
  const float* w = blockIdx.z ? wB : wA;
  u16* wT = blockIdx.z ? wBT : wAT;
  int k0 = blockIdx.x * 32, n0 = blockIdx.y * 32;
  int tx = threadIdx.x & 31, ty = threadIdx.x >> 5;   // 32 x 8
  #pragma unroll
  for (int p = 0; p < 4; ++p) {
    int r = ty + p * 8;
    t[r][tx] = w[(long)(k0 + r) * N + n0 + tx];
  }
  __syncthreads();
  #pragma unroll
  for (int p = 0; p < 4; ++p) {
    int r = ty + p * 8;
    wT[(long)(n0 + r) * K + k0 + tx] = f2b(t[tx][r]);
  }
}

// ---- prep: conv taps [Ca, taps] -> [taps, Ca] f32 ----
__global__ void cwt_kernel(const float* __restrict__ cw, float* __restrict__ cwT, int taps) {
  int idx = blockIdx.x * 256 + threadIdx.x;
  if (idx >= taps * CAc) return;
  int t = idx / CAc, c = idx - t * CAc;
  cwT[idx] = cw[c * taps + t];
}

// ---- prep: per-thread t-loop; x read once; xb=bf16(xs), db=bf16(xs-prev) ----
__global__ void prep_kernel(const float* __restrict__ x, u16* __restrict__ xb, u16* __restrict__ db) {
  int idx = blockIdx.x * 256 + threadIdx.x;  // 16*196*96 = 301056 threads
  int c8 = idx % 96;
  int rest = idx / 96;
  int hw = rest % HWc;
  int b = rest / HWc;
  int c0 = c8 * 8;
  f32x4 pa, pb;
  #pragma unroll
  for (int t = 0; t < Tc; ++t) {
    long xoff = ((long)(b * Tc + t) * Lc + 1 + hw) * Cc + c0;
    f32x4 ca = *(const f32x4*)(x + xoff);
    f32x4 cb = *(const f32x4*)(x + xoff + 4);
    if (t == 0) { pa = ca; pb = cb; }
    s16x8 xo, dd;
    #pragma unroll
    for (int q = 0; q < 4; ++q) {
      xo[q]     = (short)f2b(ca[q]);
      xo[q + 4] = (short)f2b(cb[q]);
      dd[q]     = (short)f2b(ca[q] - pa[q]);
      dd[q + 4] = (short)f2b(cb[q] - pb[q]);
    }
    long r = (long)(b * Tc + t) * HWc + hw;
    *(s16x8*)(xb + r * Cc + c0) = xo;
    *(s16x8*)(db + r * Cc + c0) = dd;
    pa = ca; pb = cb;
  }
}

// ---- CLS token passthrough ----
__global__ void cls_kernel(const float* __restrict__ x, float* __restrict__ out) {
  int idx = blockIdx.x * 256 + threadIdx.x;
  if (idx >= BTc * (Cc / 4)) return;
  int bt = idx / (Cc / 4);
  int c4 = (idx - bt * (Cc / 4)) * 4;
  long o = (long)bt * Lc * Cc + c4;
  *(f32x4*)(out + o) = *(const f32x4*)(x + o);
}

#define SP 72   // padded LDS row stride (shorts)

// ---- GEMM1: [M,768]bf16 @ [768->384] + bias -> bf16 ; 1D grid, XCD-chunked ----
__global__ __launch_bounds__(256, 4) void gemm1_kernel(
    const u16* __restrict__ xb, const u16* __restrict__ db,
    const u16* __restrict__ w1T, const u16* __restrict__ ow1T,
    const float* __restrict__ b1v, const float* __restrict__ ob1v,
    u16* __restrict__ y1, u16* __restrict__ o1)
{
  __shared__ u16 lA[128 * SP];
  __shared__ u16 lB[128 * SP];
  // grid.x = 1176 = 8 XCD chunks x 147. Blocks sharing an A-tile (same m, 3 n
  // x one z) are consecutive within a chunk -> A-tile stays in that XCD's L2.
  int bid = blockIdx.x;
  int swz = (bid & 7) * 147 + (bid >> 3);
  int mt = swz / 6, r6 = swz % 6;
  int zb = r6 / 3, nt = r6 % 3;
  const u16* A    = zb ? db   : xb;
  const u16* Wt   = zb ? ow1T : w1T;
  const float* bv = zb ? ob1v : b1v;
  u16* outp       = zb ? o1   : y1;

  int tid = threadIdx.x;
  int m0 = mt * 128;
  int n0 = nt * 128;
  int wave = tid >> 6, lane = tid & 63;
  int wm = (wave >> 1) * 64, wn = (wave & 1) * 64;
  int lrow = lane & 15, lgrp = lane >> 4;
  int srow = tid >> 3;
  int scol = (tid & 7) * 8;

  f32x4 acc[4][4];
  #pragma unroll
  for (int i = 0; i < 4; ++i)
    #pragma unroll
    for (int j = 0; j < 4; ++j) acc[i][j] = (f32x4){0,0,0,0};

  for (int kt = 0; kt < 12; ++kt) {
    int k0 = kt * 64;
    #pragma unroll
    for (int p = 0; p < 4; ++p) {
      int r = p * 32 + srow;
      s16x8 va = *(const s16x8*)(A  + (long)(m0 + r) * Cc + k0 + scol);
      s16x8 vb = *(const s16x8*)(Wt + (long)(n0 + r) * Cc + k0 + scol);
      *(s16x8*)(lA + r * SP + scol) = va;
      *(s16x8*)(lB + r * SP + scol) = vb;
    }
    __syncthreads();
    #pragma unroll
    for (int kk = 0; kk < 2; ++kk) {
      s16x8 af[4], bf[4];
      #pragma unroll
      for (int i = 0; i < 4; ++i) af[i] = *(const s16x8*)(lA + (wm + i * 16 + lrow) * SP + kk * 32 + lgrp * 8);
      #pragma unroll
      for (int j = 0; j < 4; ++j) bf[j] = *(const s16x8*)(lB + (wn + j * 16 + lrow) * SP + kk * 32 + lgrp * 8);
      #pragma unroll
      for (int i = 0; i < 4; ++i)
        #pragma unroll
        for (int j = 0; j < 4; ++j)
          acc[i][j] = __builtin_amdgcn_mfma_f32_16x16x32_bf16(af[i], bf[j], acc[i][j], 0, 0, 0);
    }
    __syncthreads();
  }
  #pragma unroll
  for (int i = 0; i < 4; ++i) {
    #pragma unroll
    for (int j = 0; j < 4; ++j) {
      int n = n0 + wn + j * 16 + lrow;
      float bb = bv[n];
      #pragma unroll
      for (int q = 0; q < 4; ++q) {
        int m = m0 + wm + i * 16 + lgrp * 4 + q;
        outp[(long)m * CAc + n] = f2b(acc[i][j][q] + bb);
      }
    }
  }
}

// ---- GEMM2: out[:,1:,:] = x + c1@w2 + c2@ow2 + b2 + ob2 (f32); XCD-chunked ----
__global__ __launch_bounds__(256, 4) void gemm2_kernel(
    const u16* __restrict__ c1, const u16* __restrict__ c2,
    const u16* __restrict__ w2T, const u16* __restrict__ ow2T,
    const float* __restrict__ b2v, const float* __restrict__ ob2v,
    const float* __restrict__ x, float* __restrict__ out)
{
  __shared__ u16 lA[128 * SP];
  __shared__ u16 lB[128 * SP];
  // grid.x = 1176; 6 consecutive blocks in a chunk share the same A row-tile.
  int bid = blockIdx.x;
  int swz = (bid & 7) * 147 + (bid >> 3);
  int mt = swz / 6, nt = swz % 6;
  int tid = threadIdx.x;
  int m0 = mt * 128;
  int n0 = nt * 128;
  int wave = tid >> 6, lane = tid & 63;
  int wm = (wave >> 1) * 64, wn = (wave & 1) * 64;
  int lrow = lane & 15, lgrp = lane >> 4;
  int srow = tid >> 3;
  int scol = (tid & 7) * 8;

  f32x4 acc[4][4];
  #pragma unroll
  for (int i = 0; i < 4; ++i)
    #pragma unroll
    for (int j = 0; j < 4; ++j) acc[i][j] = (f32x4){0,0,0,0};

  for (int kt = 0; kt < 12; ++kt) {
    int half = kt >= 6;
    const u16* Ap = half ? c2 : c1;
    const u16* Wp = half ? ow2T : w2T;
    int k0 = (half ? (kt - 6) : kt) * 64;
    #pragma unroll
    for (int p = 0; p < 4; ++p) {
      int r = p * 32 + srow;
      s16x8 va = *(const s16x8*)(Ap + (long)(m0 + r) * CAc + k0 + scol);
      s16x8 vb = *(const s16x8*)(Wp + (long)(n0 + r) * CAc + k0 + scol);
      *(s16x8*)(lA + r * SP + scol) = va;
      *(s16x8*)(lB + r * SP + scol) = vb;
    }
    __syncthreads();
    #pragma unroll
    for (int kk = 0; kk < 2; ++kk) {
      s16x8 af[4], bf[4];
      #pragma unroll
      for (int i = 0; i < 4; ++i) af[i] = *(const s16x8*)(lA + (wm + i * 16 + lrow) * SP + kk * 32 + lgrp * 8);
      #pragma unroll
      for (int j = 0; j < 4; ++j) bf[j] = *(const s16x8*)(lB + (wn + j * 16 + lrow) * SP + kk * 32 + lgrp * 8);
      #pragma unroll
      for (int i = 0; i < 4; ++i)
        #pragma unroll
        for (int j = 0; j < 4; ++j)
          acc[i][j] = __builtin_amdgcn_mfma_f32_16x16x32_bf16(af[i], bf[j], acc[i][j], 0, 0, 0);
    }
    __syncthreads();
  }
  #pragma unroll
  for (int i = 0; i < 4; ++i) {
    #pragma unroll
    for (int q = 0; q < 4; ++q) {
      int m = m0 + wm + i * 16 + lgrp * 4 + q;
      int bt = m / HWc;
      int hw = m - bt * HWc;
      long base = ((long)bt * Lc + 1 + hw) * Cc;
      #pragma unroll
      for (int j = 0; j < 4; ++j) {
        int n = n0 + wn + j * 16 + lrow;
        out[base + n] = x[base + n] + acc[i][j][q] + b2v[n] + ob2v[n];
      }
    }
  }
}

// ---- depthwise conv v3: sliding-window along W, 4ch x 7 outputs per thread ----
// grid (1792, 2): x -> (bt,h) XCD-swizzled, y -> branch. block = 192 threads.
__global__ __launch_bounds__(192) void conv_kernel(
    const u16* __restrict__ in1, const float* __restrict__ wT1,
    const float* __restrict__ bias1, u16* __restrict__ out1,
    const u16* __restrict__ in2, const float* __restrict__ wT2,
    const float* __restrict__ bias2, u16* __restrict__ out2)
{
  int bx = blockIdx.x;
  int swzx = (bx & 7) * 224 + (bx >> 3);   // bijective: 1792 = 8*224
  int is3d = (blockIdx.y == 0);
  const u16* in = is3d ? in1 : in2;
  const float* wT = is3d ? wT1 : wT2;
  const float* bias = is3d ? bias1 : bias2;
  u16* outp = is3d ? out1 : out2;

  int h = swzx % Hc;
  int bt = swzx / Hc;
  int t = bt & 7;
  int tid = threadIdx.x;
  int c4 = tid % 96;       // 96 groups of 4 channels
  int wh = tid / 96;       // half-row: outputs [wh*7, wh*7+7)
  int c0 = c4 * 4;
  int wstart = wh * 7;

  float acc[7][4];
  #pragma unroll
  for (int j = 0; j < 7; ++j)
    #pragma unroll
    for (int q = 0; q < 4; ++q) acc[j][q] = 0.f;

  int dtlo = is3d ? -1 : 0, dthi = is3d ? 1 : 0;
  for (int dt = dtlo; dt <= dthi; ++dt) {
    int tt = t + dt;
    if (tt < 0 || tt >= Tc) continue;
    for (int dh = -1; dh <= 1; ++dh) {
      int hh = h + dh;
      if (hh < 0 || hh >= Hc) continue;
      int tapbase = is3d ? ((dt + 1) * 9 + (dh + 1) * 3) : ((dh + 1) * 3);
      f32x4 k0 = *(const f32x4*)(wT + (tapbase + 0) * CAc + c0);  // dw=-1
      f32x4 k1 = *(const f32x4*)(wT + (tapbase + 1) * CAc + c0);  // dw= 0
      f32x4 k2 = *(const f32x4*)(wT + (tapbase + 2) * CAc + c0);  // dw=+1
      long rowbase = ((long)(bt + dt) * HWc + hh * Wc) * CAc + c0;
      #pragma unroll
      for (int i = 0; i < 9; ++i) {
        int col = wstart - 1 + i;
        if (col < 0 || col >= Wc) continue;
        s16x4 v = *(const s16x4*)(in + rowbase + (long)col * CAc);
        f32x4 f;
        #pragma unroll
        for (int q = 0; q < 4; ++q) f[q] = b2f((u16)v[q]);
        // in[col] contributes: out[col+1]*k0, out[col]*k1, out[col-1]*k2
        if (i <= 6) {
          for (int q = 0; q < 4; ++q) acc[i][q]     += f[q] * k0[q];
        }
        if (i >= 1 && i <= 7) {
          for (int q = 0; q < 4; ++q) acc[i - 1][q] += f[q] * k1[q];
        }
        if (i >= 2) {
          for (int q = 0; q < 4; ++q) acc[i - 2][q] += f[q] * k2[q];
        }
      }
    }
  }
  f32x4 bv = *(const f32x4*)(bias + c0);
  long obase = ((long)bt * HWc + h * Wc + wstart) * CAc + c0;
  #pragma unroll
  for (int j = 0; j < 7; ++j) {
    s16x4 o;
    #pragma unroll
    for (int q = 0; q < 4; ++q) o[q] = (short)f2b(acc[j][q] + bv[q]);
    *(s16x4*)(outp + obase + (long)j * CAc) = o;
  }
}

extern "C" void kernel_launch(void* const* d_in, const int* in_sizes, int n_in,
                              void* d_out, int out_size, void* d_ws, size_t ws_size,
                              hipStream_t stream) {
  const float* x   = (const float*)d_in[0];
  const float* w1  = (const float*)d_in[1];
  const float* b1  = (const float*)d_in[2];
  const float* cw  = (const float*)d_in[3];
  const float* cb  = (const float*)d_in[4];
  const float* w2  = (const float*)d_in[5];
  const float* b2  = (const float*)d_in[6];
  const float* ow1 = (const float*)d_in[7];
  const float* ob1 = (const float*)d_in[8];
  const float* ocw = (const float*)d_in[9];
  const float* ocb = (const float*)d_in[10];
  const float* ow2 = (const float*)d_in[11];
  const float* ob2 = (const float*)d_in[12];
  float* out = (float*)d_out;
  char* ws = (char*)d_ws;

  // workspace layout (bytes)
  u16*  w1T  = (u16*) (ws + 0);          // 589824
  u16*  ow1T = (u16*) (ws + 589824);
  u16*  w2T  = (u16*) (ws + 1179648);
  u16*  ow2T = (u16*) (ws + 1769472);
  float* cwT = (float*)(ws + 2359296);   // 41472
  float* ocwT= (float*)(ws + 2400768);   // 13824
  u16*  xb   = (u16*) (ws + 2414592);    // 38535168
  u16*  db   = (u16*) (ws + 40949760);   // 38535168
  u16*  y1   = (u16*) (ws + 79484928);   // 19267584
  u16*  o1   = (u16*) (ws + 98752512);   // 19267584; end 118020096
  u16*  c1   = (u16*) (ws + 2414592);    // alias xb (dead after gemm1)
  u16*  c2   = (u16*) (ws + 21682176);   // alias xb upper half

  wt_kernel<<<dim3(24, 12, 2), 256, 0, stream>>>(w1, w1T, ow1, ow1T, 768, 384);
  wt_kernel<<<dim3(12, 24, 2), 256, 0, stream>>>(w2, w2T, ow2, ow2T, 384, 768);
  cwt_kernel<<<41, 256, 0, stream>>>(cw, cwT, 27);
  cwt_kernel<<<14, 256, 0, stream>>>(ocw, ocwT, 9);
  cls_kernel<<<96, 256, 0, stream>>>(x, out);
  prep_kernel<<<1176, 256, 0, stream>>>(x, xb, db);
  gemm1_kernel<<<1176, 256, 0, stream>>>(xb, db, w1T, ow1T, b1, ob1, y1, o1);
  conv_kernel<<<dim3(1792, 2), 192, 0, stream>>>(y1, cwT, cb, c1, o1, ocwT, ocb, c2);
  gemm2_kernel<<<1176, 256, 0, stream>>>(c1, c2, w2T, ow2T, b2, ob2, x, out);
}